// Round 1
// baseline (17307.744 us; speedup 1.0000x reference)
//
#include <hip/hip_runtime.h>
#include <hip/hip_cooperative_groups.h>

namespace cg = cooperative_groups;

#define L_SEQ 512
#define NB    64
#define DDIM  512
#define HHALF 256
#define GG    1024   // 4*HALF

using f32x4  = __attribute__((ext_vector_type(4))) float;
using bf16x8 = __attribute__((ext_vector_type(8))) short;
using half4  = __attribute__((ext_vector_type(4))) _Float16;

__device__ __forceinline__ unsigned short f2bf(float f) {
    unsigned u = __float_as_uint(f);
    u += 0x7fffu + ((u >> 16) & 1u);          // round-to-nearest-even
    return (unsigned short)(u >> 16);
}
__device__ __forceinline__ float fsigmoid(float x) {
    return 1.0f / (1.0f + __expf(-x));
}
__device__ __forceinline__ float ftanh(float x) {
    return 1.0f - 2.0f / (__expf(2.0f * x) + 1.0f);
}

// ---------------------------------------------------------------------------
// Phase 1: xwb[dir][t][b][g] (fp16) = x[t][b][:] . W_ih[g][:] + b_ih[g] + b_hh[g]
// fp32 GEMM, M=32768 (t*64+b), N=1024 (g), K=512. Tile 128x128x8, 8x8/thread.
// ---------------------------------------------------------------------------
__global__ __launch_bounds__(256) void gemm_xwb(
    const float* __restrict__ x,
    const float* __restrict__ Wf, const float* __restrict__ Wb,
    const float* __restrict__ bihf, const float* __restrict__ bhhf,
    const float* __restrict__ bihb, const float* __restrict__ bhhb,
    _Float16* __restrict__ xwb)
{
    const int dir = blockIdx.z;
    const float* __restrict__ W   = dir ? Wb   : Wf;
    const float* __restrict__ bih = dir ? bihb : bihf;
    const float* __restrict__ bhh = dir ? bhhb : bhhf;
    const int n0 = blockIdx.x * 128;
    const int m0 = blockIdx.y * 128;

    __shared__ float As[8][128];
    __shared__ float Ws[8][128];

    const int t   = threadIdx.x;
    const int row = t >> 1;
    const int kq  = (t & 1) * 4;
    const int tm  = t >> 4;
    const int tn  = t & 15;

    float acc[8][8];
#pragma unroll
    for (int i = 0; i < 8; ++i)
#pragma unroll
        for (int jj = 0; jj < 8; ++jj) acc[i][jj] = 0.f;

    const float* xa = x + (size_t)(m0 + row) * DDIM + kq;
    const float* wa = W + (size_t)(n0 + row) * DDIM + kq;

    for (int k0 = 0; k0 < DDIM; k0 += 8) {
        float4 av = *(const float4*)(xa + k0);
        float4 wv = *(const float4*)(wa + k0);
        __syncthreads();
        As[kq + 0][row] = av.x; As[kq + 1][row] = av.y;
        As[kq + 2][row] = av.z; As[kq + 3][row] = av.w;
        Ws[kq + 0][row] = wv.x; Ws[kq + 1][row] = wv.y;
        Ws[kq + 2][row] = wv.z; Ws[kq + 3][row] = wv.w;
        __syncthreads();
#pragma unroll
        for (int k = 0; k < 8; ++k) {
            float4 a0 = *(const float4*)&As[k][tm * 4];
            float4 a1 = *(const float4*)&As[k][64 + tm * 4];
            float4 b0 = *(const float4*)&Ws[k][tn * 4];
            float4 b1 = *(const float4*)&Ws[k][64 + tn * 4];
            float aa[8] = {a0.x, a0.y, a0.z, a0.w, a1.x, a1.y, a1.z, a1.w};
            float bb[8] = {b0.x, b0.y, b0.z, b0.w, b1.x, b1.y, b1.z, b1.w};
#pragma unroll
            for (int i = 0; i < 8; ++i)
#pragma unroll
                for (int jj = 0; jj < 8; ++jj)
                    acc[i][jj] = __builtin_fmaf(aa[i], bb[jj], acc[i][jj]);
        }
    }

    float bias[8];
#pragma unroll
    for (int jj = 0; jj < 8; ++jj) {
        int col = n0 + ((jj < 4) ? (tn * 4 + jj) : (64 + tn * 4 + jj - 4));
        bias[jj] = bih[col] + bhh[col];
    }
#pragma unroll
    for (int i = 0; i < 8; ++i) {
        int m = m0 + ((i < 4) ? (tm * 4 + i) : (64 + tm * 4 + i - 4));
        _Float16* op = xwb + ((size_t)dir * (L_SEQ * NB) + m) * GG + n0;
        half4 v0, v1;
#pragma unroll
        for (int jj = 0; jj < 4; ++jj) v0[jj] = (_Float16)(acc[i][jj] + bias[jj]);
#pragma unroll
        for (int jj = 0; jj < 4; ++jj) v1[jj] = (_Float16)(acc[i][4 + jj] + bias[4 + jj]);
        *(half4*)(op + tn * 4) = v0;
        *(half4*)(op + 64 + tn * 4) = v1;
    }
}

// ---------------------------------------------------------------------------
// Phase 2: recurrence. Cooperative kernel, 128 blocks x 256 thr.
// dir = bid>>6; each block owns 4 h-cols (j0..j0+3) => 16 gate cols (one MFMA
// N-tile: col c = l&15 -> gate s=c>>2 of column j0+(c&3)).
// Wave w handles batch rows 16w..16w+15 (one MFMA M-tile).
// W_hh B-fragments register-resident (bf16). h double-buffered in ws (bf16).
// c-state lives in registers (4 per lane, redundant across the 4 gate-lanes).
// One grid.sync() per step.
// ---------------------------------------------------------------------------
__global__ __launch_bounds__(256) void lstm_recur(
    const _Float16* __restrict__ xwb,
    const float* __restrict__ Whh_f,
    const float* __restrict__ Whh_b,
    const float* __restrict__ mask,
    float* __restrict__ out,
    unsigned short* __restrict__ Hbuf)
{
    cg::grid_group grid = cg::this_grid();

    const int bid = blockIdx.x;        // 0..127
    const int dir = bid >> 6;
    const int blk = bid & 63;
    const int j0  = blk * 4;

    const int tid = threadIdx.x;
    const int w   = tid >> 6;          // wave -> M-tile (batch band)
    const int l   = tid & 63;
    const int q   = l >> 4;            // quad
    const int c   = l & 15;            // MFMA col index
    const int s   = c >> 2;            // gate index (0=i,1=f,2=g,3=o)
    const int j   = j0 + (c & 3);      // h column
    const int gcol = s * HHALF + j;    // gate column in [0,1024)

    // zero both phases of Hbuf: 2 phases * 2 dirs * 64 * 256 ushort = 32768 uints
    ((unsigned int*)Hbuf)[bid * 256 + tid] = 0u;

    // B fragments: B[k][n] = W_hh[gcol][k]; lane holds k = kt*32 + q*8 .. +7
    const float* __restrict__ Whh = dir ? Whh_b : Whh_f;
    bf16x8 bfrag[8];
#pragma unroll
    for (int kt = 0; kt < 8; ++kt) {
        const float* wp = Whh + (size_t)gcol * HHALF + kt * 32 + q * 8;
        bf16x8 v;
#pragma unroll
        for (int i = 0; i < 8; ++i) v[i] = (short)f2bf(wp[i]);
        bfrag[kt] = v;
    }

    float cstate[4] = {0.f, 0.f, 0.f, 0.f};

    __threadfence();
    grid.sync();

    for (int step = 0; step < L_SEQ; ++step) {
        const int tt = dir ? (L_SEQ - 1 - step) : step;
        const unsigned short* __restrict__ Hr =
            Hbuf + (size_t)((step & 1) * 2 + dir) * NB * HHALF;
        unsigned short* __restrict__ Hw =
            Hbuf + (size_t)(((step + 1) & 1) * 2 + dir) * NB * HHALF;

        // A fragments: A[m][k] = h_prev[16w + (l&15)][kt*32 + q*8 .. +7]
        bf16x8 afrag[8];
        const unsigned short* hp = Hr + (size_t)(16 * w + c) * HHALF;
#pragma unroll
        for (int kt = 0; kt < 8; ++kt)
            afrag[kt] = *(const bf16x8*)(hp + kt * 32 + q * 8);

        // C init from precomputed x-projection (+both biases already folded)
        f32x4 acc;
        const _Float16* xp = xwb + ((size_t)dir * L_SEQ + tt) * NB * GG + gcol;
#pragma unroll
        for (int r = 0; r < 4; ++r) {
            int b = 16 * w + q * 4 + r;
            acc[r] = (float)xp[(size_t)b * GG];
        }

#pragma unroll
        for (int kt = 0; kt < 8; ++kt)
            acc = __builtin_amdgcn_mfma_f32_16x16x32_bf16(afrag[kt], bfrag[kt], acc, 0, 0, 0);

        // elementwise: gather the 4 gates for (b, j) across lanes l^4,l^8,l^12
#pragma unroll
        for (int r = 0; r < 4; ++r) {
            const int b = 16 * w + q * 4 + r;
            float myv = acc[r];                  // gate s
            float v1 = __shfl_xor(myv, 4);       // gate s^1
            float v2 = __shfl_xor(myv, 8);       // gate s^2
            float v3 = __shfl_xor(myv, 12);      // gate s^3
            float gi = (s == 0) ? myv : ((s == 1) ? v1  : ((s == 2) ? v2  : v3));
            float gf = (s == 0) ? v1  : ((s == 1) ? myv : ((s == 2) ? v3  : v2));
            float gg = (s == 0) ? v2  : ((s == 1) ? v3  : ((s == 2) ? myv : v1));
            float go = (s == 0) ? v3  : ((s == 1) ? v2  : ((s == 2) ? v1  : myv));
            float cn = fsigmoid(gf) * cstate[r] + fsigmoid(gi) * ftanh(gg);
            float h  = fsigmoid(go) * ftanh(cn);
            float m  = mask[tt * NB + b];
            h  *= m;
            cn *= m;
            cstate[r] = cn;                      // all 4 gate-lanes keep identical copies
            if (s == 0) {
                Hw[(size_t)b * HHALF + j] = f2bf(h);
                out[((size_t)tt * NB + b) * (2 * HHALF) + dir * HHALF + j] = h;
            }
        }

        __threadfence();
        grid.sync();
    }
}

// ---------------------------------------------------------------------------
// Launcher.  Workspace layout:
//   [0, 128 MiB)        xwb   fp16 [2][512][64][1024]
//   [128 MiB, +128 KiB) Hbuf  bf16 [2 phases][2 dirs][64][256]
// Requires ws_size >= 134,348,800 bytes.
// ---------------------------------------------------------------------------
extern "C" void kernel_launch(void* const* d_in, const int* in_sizes, int n_in,
                              void* d_out, int out_size, void* d_ws, size_t ws_size,
                              hipStream_t stream)
{
    (void)in_sizes; (void)n_in; (void)out_size; (void)ws_size;
    const float* x     = (const float*)d_in[0];
    const float* mask  = (const float*)d_in[1];
    const float* Wih_f = (const float*)d_in[2];
    const float* Whh_f = (const float*)d_in[3];
    const float* bih_f = (const float*)d_in[4];
    const float* bhh_f = (const float*)d_in[5];
    const float* Wih_b = (const float*)d_in[6];
    const float* Whh_b = (const float*)d_in[7];
    const float* bih_b = (const float*)d_in[8];
    const float* bhh_b = (const float*)d_in[9];
    float* out = (float*)d_out;

    _Float16* xwb = (_Float16*)d_ws;
    unsigned short* Hbuf =
        (unsigned short*)((char*)d_ws + (size_t)2 * L_SEQ * NB * GG * sizeof(_Float16));

    hipLaunchKernelGGL(gemm_xwb, dim3(8, 256, 2), dim3(256), 0, stream,
                       x, Wih_f, Wih_b, bih_f, bhh_f, bih_b, bhh_b, xwb);

    void* args[6];
    args[0] = (void*)&xwb;
    args[1] = (void*)&Whh_f;
    args[2] = (void*)&Whh_b;
    args[3] = (void*)&mask;
    args[4] = (void*)&out;
    args[5] = (void*)&Hbuf;
    hipLaunchCooperativeKernel((const void*)lstm_recur, dim3(128), dim3(256),
                               args, 0, stream);
}

// Round 3
// 4751.147 us; speedup vs baseline: 3.6429x; 3.6429x over previous
//
#include <hip/hip_runtime.h>

#define L_SEQ 512
#define NB    64
#define DDIM  512
#define HHALF 256
#define GG    1024   // 4*HALF

using f32x4  = __attribute__((ext_vector_type(4))) float;
using bf16x8 = __attribute__((ext_vector_type(8))) short;
using half4  = __attribute__((ext_vector_type(4))) _Float16;

__device__ __forceinline__ unsigned short f2bf(float f) {
    unsigned u = __float_as_uint(f);
    u += 0x7fffu + ((u >> 16) & 1u);          // round-to-nearest-even
    return (unsigned short)(u >> 16);
}
__device__ __forceinline__ float fsigmoid(float x) {
    return 1.0f / (1.0f + __expf(-x));
}
__device__ __forceinline__ float ftanh(float x) {
    return 1.0f - 2.0f / (__expf(2.0f * x) + 1.0f);
}

// ---------------------------------------------------------------------------
// Phase 1: xwb[dir][t][b][g] (fp16) = x[t][b][:] . W_ih[g][:] + b_ih[g] + b_hh[g]
// fp32 GEMM, M=32768 (t*64+b), N=1024 (g), K=512. Tile 128x128x8, 8x8/thread.
// Block (0,0,0) additionally zero-inits Hbuf + flags (visible to lstm_recur
// via same-stream kernel ordering) — replaces hipMemsetAsync.
// ---------------------------------------------------------------------------
__global__ __launch_bounds__(256) void gemm_xwb(
    const float* __restrict__ x,
    const float* __restrict__ Wf, const float* __restrict__ Wb,
    const float* __restrict__ bihf, const float* __restrict__ bhhf,
    const float* __restrict__ bihb, const float* __restrict__ bhhb,
    _Float16* __restrict__ xwb,
    unsigned int* __restrict__ zero_base, int zero_words)
{
    const int dir = blockIdx.z;
    const float* __restrict__ W   = dir ? Wb   : Wf;
    const float* __restrict__ bih = dir ? bihb : bihf;
    const float* __restrict__ bhh = dir ? bhhb : bhhf;
    const int n0 = blockIdx.x * 128;
    const int m0 = blockIdx.y * 128;

    if (blockIdx.x == 0 && blockIdx.y == 0 && blockIdx.z == 0) {
        for (int i = threadIdx.x; i < zero_words; i += 256)
            zero_base[i] = 0u;
    }

    __shared__ float As[8][128];
    __shared__ float Ws[8][128];

    const int t   = threadIdx.x;
    const int row = t >> 1;
    const int kq  = (t & 1) * 4;
    const int tm  = t >> 4;
    const int tn  = t & 15;

    float acc[8][8];
#pragma unroll
    for (int i = 0; i < 8; ++i)
#pragma unroll
        for (int jj = 0; jj < 8; ++jj) acc[i][jj] = 0.f;

    const float* xa = x + (size_t)(m0 + row) * DDIM + kq;
    const float* wa = W + (size_t)(n0 + row) * DDIM + kq;

    for (int k0 = 0; k0 < DDIM; k0 += 8) {
        float4 av = *(const float4*)(xa + k0);
        float4 wv = *(const float4*)(wa + k0);
        __syncthreads();
        As[kq + 0][row] = av.x; As[kq + 1][row] = av.y;
        As[kq + 2][row] = av.z; As[kq + 3][row] = av.w;
        Ws[kq + 0][row] = wv.x; Ws[kq + 1][row] = wv.y;
        Ws[kq + 2][row] = wv.z; Ws[kq + 3][row] = wv.w;
        __syncthreads();
#pragma unroll
        for (int k = 0; k < 8; ++k) {
            float4 a0 = *(const float4*)&As[k][tm * 4];
            float4 a1 = *(const float4*)&As[k][64 + tm * 4];
            float4 b0 = *(const float4*)&Ws[k][tn * 4];
            float4 b1 = *(const float4*)&Ws[k][64 + tn * 4];
            float aa[8] = {a0.x, a0.y, a0.z, a0.w, a1.x, a1.y, a1.z, a1.w};
            float bb[8] = {b0.x, b0.y, b0.z, b0.w, b1.x, b1.y, b1.z, b1.w};
#pragma unroll
            for (int i = 0; i < 8; ++i)
#pragma unroll
                for (int jj = 0; jj < 8; ++jj)
                    acc[i][jj] = __builtin_fmaf(aa[i], bb[jj], acc[i][jj]);
        }
    }

    float bias[8];
#pragma unroll
    for (int jj = 0; jj < 8; ++jj) {
        int col = n0 + ((jj < 4) ? (tn * 4 + jj) : (64 + tn * 4 + jj - 4));
        bias[jj] = bih[col] + bhh[col];
    }
#pragma unroll
    for (int i = 0; i < 8; ++i) {
        int m = m0 + ((i < 4) ? (tm * 4 + i) : (64 + tm * 4 + i - 4));
        _Float16* op = xwb + ((size_t)dir * (L_SEQ * NB) + m) * GG + n0;
        half4 v0, v1;
#pragma unroll
        for (int jj = 0; jj < 4; ++jj) v0[jj] = (_Float16)(acc[i][jj] + bias[jj]);
#pragma unroll
        for (int jj = 0; jj < 4; ++jj) v1[jj] = (_Float16)(acc[i][4 + jj] + bias[4 + jj]);
        *(half4*)(op + tn * 4) = v0;
        *(half4*)(op + 64 + tn * 4) = v1;
    }
}

// ---------------------------------------------------------------------------
// Phase 2: recurrence with 8 independent sync-groups. PLAIN launch (32 blocks
// on 256 CUs are always co-resident; no cooperative API needed).
// Group = (dir, batch-group of 16 rows); 4 blocks/group split 256 h-cols
// into 64-col slices. bid&7 = group, bid>>3 = slice.
// Block = 256 thr = 4 waves. Wave w owns cols 16w..16w+15 of its slice for
// all 4 gates => lane (q,c) holds gates i,f,g,o of h-col j for batch rows
// b0+q*4+r in acc[0..3][r] — no shuffles, c-state 4 regs/lane.
// W_hh slice register-resident (128 VGPRs bf16). Barrier = cumulative counter
// per group: release atomicAdd by tid0 after fence, acquire spin by tid0.
// Hbuf double-buffered. Hbuf+flags zeroed by gemm_xwb (prior kernel, same
// stream).
// ---------------------------------------------------------------------------
__global__ __launch_bounds__(256, 1) void lstm_recur(
    const _Float16* __restrict__ xwb,
    const float* __restrict__ Whh_f,
    const float* __restrict__ Whh_b,
    const float* __restrict__ mask,
    float* __restrict__ out,
    unsigned short* __restrict__ Hbuf,    // [phase][dir][64][256] bf16
    unsigned int* __restrict__ flags)     // [8] stride 32 uints
{
    const int bid = blockIdx.x;           // 0..31
    const int grp = bid & 7;              // dir*4 + gb
    const int dir = grp >> 2;
    const int gb  = grp & 3;
    const int g   = bid >> 3;             // h-col slice 0..3
    unsigned int* cnt = flags + grp * 32;

    const int tid = threadIdx.x;
    const int w   = tid >> 6;
    const int l   = tid & 63;
    const int q   = l >> 4;
    const int c   = l & 15;

    const int b0 = gb * 16;               // group's batch base
    const int j  = 64 * g + 16 * w + c;   // h column [0,256)

    // --- B fragments: W_hh slice, register resident ---
    // gate t: B[k][n=c] = W_hh[t*256 + j][k], lane k-range kt*32+q*8..+7
    const float* __restrict__ Whh = dir ? Whh_b : Whh_f;
    bf16x8 bfrag[4][8];
#pragma unroll
    for (int t = 0; t < 4; ++t) {
        const int gcol = t * HHALF + j;
#pragma unroll
        for (int kt = 0; kt < 8; ++kt) {
            const float4* wp = (const float4*)(Whh + (size_t)gcol * HHALF + kt * 32 + q * 8);
            float4 w0 = wp[0], w1 = wp[1];
            bf16x8 v;
            v[0] = (short)f2bf(w0.x); v[1] = (short)f2bf(w0.y);
            v[2] = (short)f2bf(w0.z); v[3] = (short)f2bf(w0.w);
            v[4] = (short)f2bf(w1.x); v[5] = (short)f2bf(w1.y);
            v[6] = (short)f2bf(w1.z); v[7] = (short)f2bf(w1.w);
            bfrag[t][kt] = v;
        }
    }

    float cstate[4] = {0.f, 0.f, 0.f, 0.f};

    for (int step = 0; step < L_SEQ; ++step) {
        const int tt = dir ? (L_SEQ - 1 - step) : step;

        // ---- prefetch (independent of h): xwb + mask for this step ----
        float xv[4][4];
        const _Float16* xp = xwb + ((size_t)(dir * L_SEQ + tt) * NB + b0 + q * 4) * GG + j;
#pragma unroll
        for (int t = 0; t < 4; ++t)
#pragma unroll
            for (int r = 0; r < 4; ++r)
                xv[t][r] = (float)xp[(size_t)r * GG + t * HHALF];
        float mv[4];
#pragma unroll
        for (int r = 0; r < 4; ++r) mv[r] = mask[tt * NB + b0 + q * 4 + r];

        // ---- wait for peers' h of step-1 ----
        if (tid == 0) {
            const unsigned target = 4u * (unsigned)step;
            while (__hip_atomic_load(cnt, __ATOMIC_ACQUIRE, __HIP_MEMORY_SCOPE_AGENT) < target) {}
        }
        __syncthreads();

        const unsigned short* __restrict__ Hr =
            Hbuf + (size_t)((step & 1) * 2 + dir) * NB * HHALF;
        unsigned short* __restrict__ Hw =
            Hbuf + (size_t)(((step + 1) & 1) * 2 + dir) * NB * HHALF;

        // ---- A fragments: h rows b0..b0+15, full K=256 ----
        bf16x8 afrag[8];
        const unsigned short* hp = Hr + (size_t)(b0 + c) * HHALF;
#pragma unroll
        for (int kt = 0; kt < 8; ++kt)
            afrag[kt] = *(const bf16x8*)(hp + kt * 32 + q * 8);

        // ---- gates = xW (+biases) + h @ W_hh^T ----
        f32x4 acc[4];
#pragma unroll
        for (int t = 0; t < 4; ++t) {
            f32x4 a; a[0] = xv[t][0]; a[1] = xv[t][1]; a[2] = xv[t][2]; a[3] = xv[t][3];
            acc[t] = a;
        }
#pragma unroll
        for (int kt = 0; kt < 8; ++kt)
#pragma unroll
            for (int t = 0; t < 4; ++t)
                acc[t] = __builtin_amdgcn_mfma_f32_16x16x32_bf16(afrag[kt], bfrag[t][kt], acc[t], 0, 0, 0);

        // ---- elementwise: lane holds i,f,g,o for (b0+q*4+r, j) ----
#pragma unroll
        for (int r = 0; r < 4; ++r) {
            float gi = acc[0][r], gf = acc[1][r], gg = acc[2][r], go = acc[3][r];
            float cn = fsigmoid(gf) * cstate[r] + fsigmoid(gi) * ftanh(gg);
            float h  = fsigmoid(go) * ftanh(cn);
            float m  = mv[r];
            h  *= m;
            cn *= m;
            cstate[r] = cn;
            const int b = b0 + q * 4 + r;
            Hw[(size_t)b * HHALF + j] = f2bf(h);
            out[((size_t)tt * NB + b) * (2 * HHALF) + dir * HHALF + j] = h;
        }

        // ---- publish: fence, block-sync, single release-arrival ----
        __threadfence();
        __syncthreads();
        if (tid == 0)
            __hip_atomic_fetch_add(cnt, 1u, __ATOMIC_RELEASE, __HIP_MEMORY_SCOPE_AGENT);
    }
}

// ---------------------------------------------------------------------------
// Workspace layout:
//   [0, 128 MiB)            xwb   fp16 [2][512][64][1024]
//   [+0,   +128 KiB)        Hbuf  bf16 [2 phases][2 dirs][64][256]
//   [+128K, +1 KiB)         flags u32 [8] stride 32
// Requires ws_size >= 134,349,824 bytes.
// ---------------------------------------------------------------------------
extern "C" void kernel_launch(void* const* d_in, const int* in_sizes, int n_in,
                              void* d_out, int out_size, void* d_ws, size_t ws_size,
                              hipStream_t stream)
{
    (void)in_sizes; (void)n_in; (void)out_size; (void)ws_size;
    const float* x     = (const float*)d_in[0];
    const float* mask  = (const float*)d_in[1];
    const float* Wih_f = (const float*)d_in[2];
    const float* Whh_f = (const float*)d_in[3];
    const float* bih_f = (const float*)d_in[4];
    const float* bhh_f = (const float*)d_in[5];
    const float* Wih_b = (const float*)d_in[6];
    const float* Whh_b = (const float*)d_in[7];
    const float* bih_b = (const float*)d_in[8];
    const float* bhh_b = (const float*)d_in[9];
    float* out = (float*)d_out;

    const size_t xwb_bytes  = (size_t)2 * L_SEQ * NB * GG * sizeof(_Float16);
    const size_t hbuf_bytes = (size_t)2 * 2 * NB * HHALF * sizeof(unsigned short);
    _Float16*       xwb   = (_Float16*)d_ws;
    unsigned short* Hbuf  = (unsigned short*)((char*)d_ws + xwb_bytes);
    unsigned int*   flags = (unsigned int*)((char*)d_ws + xwb_bytes + hbuf_bytes);

    // gemm_xwb also zero-inits Hbuf + flags (33,024 words) from block (0,0,0)
    const int zero_words = (int)((hbuf_bytes + 8 * 32 * sizeof(unsigned int)) / 4);
    hipLaunchKernelGGL(gemm_xwb, dim3(8, 256, 2), dim3(256), 0, stream,
                       x, Wih_f, Wih_b, bih_f, bhh_f, bih_b, bhh_b, xwb,
                       (unsigned int*)Hbuf, zero_words);

    hipLaunchKernelGGL(lstm_recur, dim3(32), dim3(256), 0, stream,
                       xwb, Whh_f, Whh_b, mask, out, Hbuf, flags);
}